// Round 10
// baseline (263.771 us; speedup 1.0000x reference)
//
#include <hip/hip_runtime.h>

#define NB 32768
#define DD 16
#define HH 64
#define EPB 16

typedef __attribute__((ext_vector_type(8))) short short8;
typedef __attribute__((ext_vector_type(2))) float f32x2;
typedef __attribute__((ext_vector_type(4))) float f32x4;
typedef __attribute__((ext_vector_type(4))) unsigned uint4v;

union Frag { short8 s; uint4v u; unsigned d[4]; };

struct Params {
  const float *ts, *x0;
  const float *W0,*b0,*g0,*gb0,*hb0;
  const float *W1,*b1,*g1,*gb1,*hb1;
  const float *W2,*b2,*g2,*gb2,*hb2;
  const float *W3,*b3,*g3,*gb3,*hb3;
  float *out;
};

__device__ __forceinline__ unsigned short f2bf(float f){   // full RNE (init only)
  unsigned u=__float_as_uint(f);
  return (unsigned short)((u + 0x7FFFu + ((u>>16)&1u))>>16);
}
__device__ __forceinline__ unsigned pk2bf(float lo, float hi){
  unsigned a=__float_as_uint(lo)+0x8000u;
  unsigned b=__float_as_uint(hi)+0x8000u;
  return __builtin_amdgcn_perm(b, a, 0x07060302u);
}
__device__ __forceinline__ unsigned pk2bf2(f32x2 v){
  unsigned a=__float_as_uint(v[0])+0x8000u;
  unsigned b=__float_as_uint(v[1])+0x8000u;
  return __builtin_amdgcn_perm(b, a, 0x07060302u);
}
__device__ __forceinline__ unsigned short f2bf1(float f){
  return (unsigned short)((__float_as_uint(f)+0x8000u)>>16);
}
__device__ __forceinline__ float sigm(float u){
  return __builtin_amdgcn_rcpf(1.0f+__builtin_amdgcn_exp2f(-1.44269504f*u));
}
#define WV() __builtin_amdgcn_wave_barrier()
#define MFMA(A,B,C) __builtin_amdgcn_mfma_f32_16x16x32_bf16((A),(B),(C),0,0,0)

// gated-tanh epilogue (pk form); sc = {g, gb, hb, b}
__device__ __forceinline__ void fwd_epi(const f32x4& c, float tcur,
    const float4 sc,
    unsigned short* __restrict__ hdst, float* __restrict__ sdst,
    int jw, int q)
{
  const float gate = sigm(tcur*sc.x+sc.y);
  const float gk   = gate*2.88539008f;
  const float tbk  = (tcur*sc.z)*2.88539008f;
  const float g4   = 4.0f*gate;
  const f32x2 c01={c[0],c[1]}, c23={c[2],c[3]};
  const f32x2 pre01 = c01*gk + tbk;
  const f32x2 pre23 = c23*gk + tbk;
  const f32x2 e01={__builtin_amdgcn_exp2f(pre01[0]),__builtin_amdgcn_exp2f(pre01[1])};
  const f32x2 e23={__builtin_amdgcn_exp2f(pre23[0]),__builtin_amdgcn_exp2f(pre23[1])};
  const f32x2 d01=e01+1.0f, d23=e23+1.0f;
  const f32x2 rc01={__builtin_amdgcn_rcpf(d01[0]),__builtin_amdgcn_rcpf(d01[1])};
  const f32x2 rc23={__builtin_amdgcn_rcpf(d23[0]),__builtin_amdgcn_rcpf(d23[1])};
  const f32x2 th01 = rc01*-2.0f + 1.0f;
  const f32x2 th23 = rc23*-2.0f + 1.0f;
  const f32x2 om01 = 1.0f - rc01, om23 = 1.0f - rc23;
  const f32x2 sv01 = (rc01*g4)*om01, sv23 = (rc23*g4)*om23;
  const int el0=q*4;
  hdst[(el0+0)*72+jw]=f2bf1(th01[0]);
  hdst[(el0+1)*72+jw]=f2bf1(th01[1]);
  hdst[(el0+2)*72+jw]=f2bf1(th23[0]);
  hdst[(el0+3)*72+jw]=f2bf1(th23[1]);
  sdst[(el0+0)*68+jw]=sv01[0];
  sdst[(el0+1)*68+jw]=sv01[1];
  sdst[(el0+2)*68+jw]=sv23[0];
  sdst[(el0+3)*68+jw]=sv23[1];
}

// (256,3): cap 170 combined. R9 spilled ~30-40 regs past it (FETCH 38 MB);
// b2fr->LDS frees 32. If FETCH_SIZE still MBs -> revert to (256,2).
__global__ __launch_bounds__(256,3) void traj_kernel(Params p){
  __shared__ __align__(16) unsigned short w0b[DD][72];     // W0[a][i] bf16 (tangent A0)
  __shared__ __align__(16) float w3tt[HH][20];             // W3[j][a] fp32 (trace)
  __shared__ __align__(16) unsigned short w0t[HH][16];     // W0^T[jw][k<16] bf16 (L0 B-frag)
  __shared__ __align__(16) unsigned short b3f[2][64][8];   // L3 B-frags (lane-only)
  __shared__ __align__(16) unsigned short w2tf[2][4][64][8]; // tangent W2 B-frags (lane-only)
  __shared__ __align__(16) float4 lscA[3][64];             // {g,gb,hb,b} per col, layers 0-2
  __shared__ __align__(16) float4 lsc3[16];                // layer 3 (by m)
  __shared__ __align__(16) unsigned short xh[DD][40];      // x hi-bf16, K=32 zero-padded
  __shared__ __align__(16) unsigned short xl[DD][40];      // x lo-bf16
  __shared__ __align__(16) unsigned short hbh[2][EPB][72]; // bf16 activations (ping-pong)
  __shared__ __align__(16) float sbf[3][EPB][68];          // s0,s1,s2 fp32
  __shared__ __align__(16) float sig3w[4][DD];
  __shared__ __align__(16) float dxs[4][4][17];            // per-wave dx slice [wv][r][m]
  __shared__ __align__(16) unsigned short vt[4][DD][72];   // per-wave V1

  const int tid = threadIdx.x;
  const int e   = tid>>4;
  const int a   = tid&15;
  const int wv  = tid>>6;
  const int lane= tid&63;
  const int m   = lane&15;
  const int q   = lane>>4;
  const int b   = blockIdx.x*EPB + e;
  const int jw  = wv*16 + m;     // forward output column of this lane

  // ---- persistent register weight fragments (wave-dep or hottest reuse) ----
  short8 f1fr[2], f2fr[2];
  short8 b1fr[2][4];              // tangent GEMM1 B-frags, N-permuted: cols 4m+nt
  {
    #pragma unroll
    for(int kk=0;kk<2;++kk){
      #pragma unroll
      for(int j=0;j<8;++j){
        const int k=kk*32+q*8+j;
        f1fr[kk][j]=(short)f2bf(p.W1[k*HH+jw]);
        f2fr[kk][j]=(short)f2bf(p.W2[k*HH+jw]);
      }
      #pragma unroll
      for(int nt=0;nt<4;++nt){
        #pragma unroll
        for(int j=0;j<8;++j){
          const int k=kk*32+q*8+j;
          b1fr[kk][nt][j]=(short)f2bf(p.W1[k*HH+4*m+nt]);
        }
      }
    }
  }

  // ---- one-time LDS staging ----
  for(int idx=tid; idx<DD*HH; idx+=256) w0b[idx>>6][idx&63]=f2bf(p.W0[idx]);
  for(int idx=tid; idx<HH*DD; idx+=256) w3tt[idx>>4][idx&15]=p.W3[idx];   // fp32
  for(int idx=tid; idx<HH*16; idx+=256){
    const int c_=idx>>4, k=idx&15;
    w0t[c_][k]=f2bf(p.W0[k*HH+c_]);
  }
  for(int idx=tid; idx<1024; idx+=256){
    const int kk=idx>>9, ln=(idx>>3)&63, j=idx&7;
    const int k=kk*32+(ln>>4)*8+j;
    b3f[kk][ln][j]=f2bf(p.W3[k*DD+(ln&15)]);
  }
  for(int idx=tid; idx<4096; idx+=256){       // tangent W2 B-frags
    const int j=idx&7, ln=(idx>>3)&63, nt=(idx>>9)&3, kk=idx>>11;
    const int k=kk*32+((ln>>4)&3)*8+j;
    w2tf[kk][nt][ln][j]=f2bf(p.W2[k*HH+4*(ln&15)+nt]);
  }
  if(tid<64)            lscA[0][tid]    =make_float4(p.g0[tid],p.gb0[tid],p.hb0[tid],p.b0[tid]);
  else if(tid<128)      lscA[1][tid-64] =make_float4(p.g1[tid-64],p.gb1[tid-64],p.hb1[tid-64],p.b1[tid-64]);
  else if(tid<192)      lscA[2][tid-128]=make_float4(p.g2[tid-128],p.gb2[tid-128],p.hb2[tid-128],p.b2[tid-128]);
  else if(tid<208)      lsc3[tid-192]   =make_float4(p.g3[tid-192],p.gb3[tid-192],p.hb3[tid-192],p.b3[tid-192]);
  if(tid<128){                                 // zero K=16..31 pad of xh/xl
    const int mm=tid>>3, dd=8+(tid&7);
    reinterpret_cast<unsigned*>(xh)[mm*20+dd]=0;
    reinterpret_cast<unsigned*>(xl)[mm*20+dd]=0;
  }
  __syncthreads();

  float zbx = p.x0[b*DD+a];
  p.out[b*DD+a]=zbx;
  float trp[4]={0.f,0.f,0.f,0.f};
  float dvp=0.f;

  #pragma unroll 1
  for(int step=0; step<2; ++step){
    const float t0=p.ts[step], t1=p.ts[step+1];
    const float hs=t1-t0;
    float dzx=0.f;
    float zwx=zbx;
    #pragma unroll 1
    for(int stage=0; stage<4; ++stage){
      const float cin=(stage==0)?0.f:((stage==3)?1.f:0.5f);
      const float tcur=t0+cin*hs;
      const float wg=(stage==0||stage==3)?1.f:2.f;
      const float fs=hs*(1.f/6.f)*wg;
      const float fs5=0.5f*fs;

      // producer writes x as pre-split hi/lo bf16
      {
        const unsigned ux=__float_as_uint(zwx);
        xh[e][a]=(unsigned short)(ux>>16);
        xl[e][a]=f2bf1(zwx-__uint_as_float(ux&0xFFFF0000u));
      }
      __syncthreads();                       // B1

      // ---------- L0: X @ W0 (hi/lo, K=32; k>=16 rows zero via zero frag) ----------
      float4 sc0=lscA[0][jw];
      f32x4 c={sc0.w,sc0.w,sc0.w,sc0.w};
      {
        short8 f0fr=short8{0,0,0,0,0,0,0,0};
        if(q<2) f0fr=*reinterpret_cast<const short8*>(&w0t[jw][q*8]);
        const short8 ah=*reinterpret_cast<const short8*>(&xh[m][q*8]);
        const short8 al=*reinterpret_cast<const short8*>(&xl[m][q*8]);
        c=MFMA(ah,f0fr,c); c=MFMA(al,f0fr,c);
      }
      fwd_epi(c,tcur,sc0,&hbh[0][0][0],&sbf[0][0][0],jw,q);
      __syncthreads();                       // B2

      // ---------- L1 ----------
      float4 sc1=lscA[1][jw];
      c=f32x4{sc1.w,sc1.w,sc1.w,sc1.w};
      #pragma unroll
      for(int kk=0;kk<2;++kk){
        const short8 ah=*reinterpret_cast<const short8*>(&hbh[0][m][kk*32+q*8]);
        c=MFMA(ah,f1fr[kk],c);
      }
      fwd_epi(c,tcur,sc1,&hbh[1][0][0],&sbf[1][0][0],jw,q);
      __syncthreads();                       // B3

      // ---------- L2 ----------
      float4 sc2=lscA[2][jw];
      c=f32x4{sc2.w,sc2.w,sc2.w,sc2.w};
      #pragma unroll
      for(int kk=0;kk<2;++kk){
        const short8 ah=*reinterpret_cast<const short8*>(&hbh[1][m][kk*32+q*8]);
        c=MFMA(ah,f2fr[kk],c);
      }
      fwd_epi(c,tcur,sc2,&hbh[0][0][0],&sbf[2][0][0],jw,q);  // h2 -> buf0
      __syncthreads();                       // B4

      // ---------- L3: dx ----------
      float4 sc3=lsc3[m];
      c=f32x4{sc3.w,sc3.w,sc3.w,sc3.w};
      #pragma unroll
      for(int kk=0;kk<2;++kk){
        const short8 bf3=*reinterpret_cast<const short8*>(&b3f[kk][lane][0]);
        const short8 ah=*reinterpret_cast<const short8*>(&hbh[0][m][kk*32+q*8]);
        c=MFMA(ah,bf3,c);
      }
      const float gate3=sigm(tcur*sc3.x+sc3.y);
      const float tb3=tcur*sc3.z;
      if(q==wv){
        #pragma unroll
        for(int r=0;r<4;++r)
          dxs[wv][r][m]=c[r]*gate3+tb3;
      }
      if(q==0) sig3w[wv][m]=gate3;
      WV();
      const float dxk=dxs[wv][q][m];         // = dx[e][a]
      dvp += fs5*dxk*dxk;

      // ---------- trace factors (once per stage, pk) ----------
      f32x2 tf2[4][2];
      {
        const f32x4 sg4=*reinterpret_cast<const f32x4*>(&sig3w[wv][q*4]);
        const f32x2 sgA={sg4[0],sg4[1]}, sgB={sg4[2],sg4[3]};
        #pragma unroll
        for(int nt=0;nt<4;++nt){
          const f32x4 w4=*reinterpret_cast<const f32x4*>(&w3tt[4*m+nt][q*4]);
          tf2[nt][0]=sgA*f32x2{w4[0],w4[1]};
          tf2[nt][1]=sgB*f32x2{w4[2],w4[3]};
        }
      }

      // ---------- tangent per element (nt-paired accumulators) ----------
      #pragma unroll
      for(int el=0; el<4; ++el){
        const int ee=wv*4+el;
        // A0 = W0 (bf16) ⊙ s0 (fp32)
        Frag a0[2];
        #pragma unroll
        for(int kk=0;kk<2;++kk){
          const uint4v wd=*reinterpret_cast<const uint4v*>(&w0b[m][kk*32+q*8]);
          const f32x4 sA=*reinterpret_cast<const f32x4*>(&sbf[0][ee][kk*32+q*8]);
          const f32x4 sB=*reinterpret_cast<const f32x4*>(&sbf[0][ee][kk*32+q*8+4]);
          #pragma unroll
          for(int d=0;d<4;++d){
            const unsigned w2d=wd[d];
            const f32x2 w2={__uint_as_float(w2d<<16),__uint_as_float(w2d&0xFFFF0000u)};
            const f32x2 s2=(d<2)? f32x2{sA[2*d],sA[2*d+1]} : f32x2{sB[2*d-4],sB[2*d-3]};
            a0[kk].d[d]=pk2bf2(w2*s2);
          }
        }
        // GEMM1 in nt pairs: only 2 acc quads live
        #pragma unroll
        for(int np=0; np<2; ++np){
          f32x4 cA={0,0,0,0}, cB={0,0,0,0};
          #pragma unroll
          for(int kk=0;kk<2;++kk){
            cA=MFMA(a0[kk].s,b1fr[kk][2*np  ],cA);
            cB=MFMA(a0[kk].s,b1fr[kk][2*np+1],cB);
          }
          const f32x2 s1v=*reinterpret_cast<const f32x2*>(&sbf[1][ee][4*m+2*np]);
          const f32x4 prA=cA*s1v[0], prB=cB*s1v[1];
          #pragma unroll
          for(int r=0;r<4;++r)
            *reinterpret_cast<unsigned*>(&vt[wv][q*4+r][4*m+2*np])=pk2bf(prA[r],prB[r]);
        }
        WV();
        short8 a2[2];
        #pragma unroll
        for(int kk=0;kk<2;++kk)
          a2[kk]=*reinterpret_cast<const short8*>(&vt[wv][m][kk*32+q*8]);
        // GEMM2 in nt pairs, B-frags streamed from LDS (lane-only table)
        float tr=0.f;
        #pragma unroll
        for(int np=0; np<2; ++np){
          f32x4 cA={0,0,0,0}, cB={0,0,0,0};
          #pragma unroll
          for(int kk=0;kk<2;++kk){
            const short8 bA=*reinterpret_cast<const short8*>(&w2tf[kk][2*np  ][lane][0]);
            const short8 bB=*reinterpret_cast<const short8*>(&w2tf[kk][2*np+1][lane][0]);
            cA=MFMA(a2[kk],bA,cA);
            cB=MFMA(a2[kk],bB,cB);
          }
          const f32x2 s2v=*reinterpret_cast<const f32x2*>(&sbf[2][ee][4*m+2*np]);
          const f32x2 tA = f32x2{cA[0],cA[1]}*tf2[2*np  ][0] + f32x2{cA[2],cA[3]}*tf2[2*np  ][1];
          const f32x2 tB = f32x2{cB[0],cB[1]}*tf2[2*np+1][0] + f32x2{cB[2],cB[3]}*tf2[2*np+1][1];
          tr += (tA[0]+tA[1])*s2v[0] + (tB[0]+tB[1])*s2v[1];
        }
        trp[el] += fs*tr;
        WV();
      }

      // ---------- RK4 state update ----------
      dzx += fs*dxk;
      const float cn=(stage==2)?1.f:0.5f;
      if(stage<3) zwx=zbx+cn*hs*dxk;
    }
    zbx += dzx;
    p.out[(step+1)*(NB*DD)+b*DD+a]=zbx;
  }

  // ---------- deferred reductions ----------
  #pragma unroll
  for(int el=0; el<4; ++el){
    float v=trp[el];
    #pragma unroll
    for(int mk=32;mk>=1;mk>>=1) v+=__shfl_xor(v,mk,64);
    if(lane==el) p.out[3*NB*DD + blockIdx.x*EPB + wv*4 + el]=v;
  }
  {
    float v=dvp;
    #pragma unroll
    for(int mk=8;mk>=1;mk>>=1) v+=__shfl_xor(v,mk,16);
    if(a==0){
      p.out[3*NB*DD+NB+b]=fabsf(v);
      p.out[3*NB*DD+2*NB+b]=0.f;
    }
  }
}

extern "C" void kernel_launch(void* const* d_in, const int* in_sizes, int n_in,
                              void* d_out, int out_size, void* d_ws, size_t ws_size,
                              hipStream_t stream){
  Params p;
  p.ts  = (const float*)d_in[0];
  p.x0  = (const float*)d_in[1];
  p.W0  = (const float*)d_in[2];  p.b0 =(const float*)d_in[3];
  p.g0  = (const float*)d_in[4];  p.gb0=(const float*)d_in[5];  p.hb0=(const float*)d_in[6];
  p.W1  = (const float*)d_in[7];  p.b1 =(const float*)d_in[8];
  p.g1  = (const float*)d_in[9];  p.gb1=(const float*)d_in[10]; p.hb1=(const float*)d_in[11];
  p.W2  = (const float*)d_in[12]; p.b2 =(const float*)d_in[13];
  p.g2  = (const float*)d_in[14]; p.gb2=(const float*)d_in[15]; p.hb2=(const float*)d_in[16];
  p.W3  = (const float*)d_in[17]; p.b3 =(const float*)d_in[18];
  p.g3  = (const float*)d_in[19]; p.gb3=(const float*)d_in[20]; p.hb3=(const float*)d_in[21];
  p.out = (float*)d_out;
  hipLaunchKernelGGL(traj_kernel, dim3(NB/EPB), dim3(256), 0, stream, p);
}

// Round 11
// 235.248 us; speedup vs baseline: 1.1212x; 1.1212x over previous
//
#include <hip/hip_runtime.h>

#define NB 32768
#define DD 16
#define HH 64
#define EPB 16

typedef __attribute__((ext_vector_type(8))) short short8;
typedef __attribute__((ext_vector_type(2))) float f32x2;
typedef __attribute__((ext_vector_type(4))) float f32x4;
typedef __attribute__((ext_vector_type(4))) unsigned uint4v;

union Frag { short8 s; uint4v u; unsigned d[4]; };

struct Params {
  const float *ts, *x0;
  const float *W0,*b0,*g0,*gb0,*hb0;
  const float *W1,*b1,*g1,*gb1,*hb1;
  const float *W2,*b2,*g2,*gb2,*hb2;
  const float *W3,*b3,*g3,*gb3,*hb3;
  float *out;
};

__device__ __forceinline__ float bfs(unsigned short u){
  return __uint_as_float(((unsigned)u)<<16);
}
__device__ __forceinline__ unsigned short f2bf(float f){   // full RNE (init only)
  unsigned u=__float_as_uint(f);
  return (unsigned short)((u + 0x7FFFu + ((u>>16)&1u))>>16);
}
__device__ __forceinline__ unsigned pk2bf(float lo, float hi){
  unsigned a=__float_as_uint(lo)+0x8000u;
  unsigned b=__float_as_uint(hi)+0x8000u;
  return __builtin_amdgcn_perm(b, a, 0x07060302u);
}
__device__ __forceinline__ unsigned short f2bf1(float f){
  return (unsigned short)((__float_as_uint(f)+0x8000u)>>16);
}
__device__ __forceinline__ float sigm(float u){
  return __builtin_amdgcn_rcpf(1.0f+__builtin_amdgcn_exp2f(-1.44269504f*u));
}
#define WV() __builtin_amdgcn_wave_barrier()
#define MFMA(A,B,C) __builtin_amdgcn_mfma_f32_16x16x32_bf16((A),(B),(C),0,0,0)

// gated-tanh epilogue; sc = {g, gb, hb, b}; h -> bf16, s -> bf16
__device__ __forceinline__ void fwd_epi(const f32x4& c, float tcur,
    const float4 sc,
    unsigned short* __restrict__ hdst, unsigned short* __restrict__ sdst,
    int jw, int q)
{
  const float gate = sigm(tcur*sc.x+sc.y);
  const float gk   = gate*2.88539008f;
  const float tbk  = (tcur*sc.z)*2.88539008f;
  const float g4   = 4.0f*gate;
  const f32x2 c01={c[0],c[1]}, c23={c[2],c[3]};
  const f32x2 pre01 = c01*gk + tbk;
  const f32x2 pre23 = c23*gk + tbk;
  const f32x2 e01={__builtin_amdgcn_exp2f(pre01[0]),__builtin_amdgcn_exp2f(pre01[1])};
  const f32x2 e23={__builtin_amdgcn_exp2f(pre23[0]),__builtin_amdgcn_exp2f(pre23[1])};
  const f32x2 d01=e01+1.0f, d23=e23+1.0f;
  const f32x2 rc01={__builtin_amdgcn_rcpf(d01[0]),__builtin_amdgcn_rcpf(d01[1])};
  const f32x2 rc23={__builtin_amdgcn_rcpf(d23[0]),__builtin_amdgcn_rcpf(d23[1])};
  const f32x2 th01 = rc01*-2.0f + 1.0f;
  const f32x2 th23 = rc23*-2.0f + 1.0f;
  const f32x2 om01 = 1.0f - rc01, om23 = 1.0f - rc23;
  const f32x2 sv01 = (rc01*g4)*om01, sv23 = (rc23*g4)*om23;
  const int el0=q*4;
  hdst[(el0+0)*72+jw]=f2bf1(th01[0]);
  hdst[(el0+1)*72+jw]=f2bf1(th01[1]);
  hdst[(el0+2)*72+jw]=f2bf1(th23[0]);
  hdst[(el0+3)*72+jw]=f2bf1(th23[1]);
  sdst[(el0+0)*72+jw]=f2bf1(sv01[0]);
  sdst[(el0+1)*72+jw]=f2bf1(sv01[1]);
  sdst[(el0+2)*72+jw]=f2bf1(sv23[0]);
  sdst[(el0+3)*72+jw]=f2bf1(sv23[1]);
}

// (256,3): cap 170 combined — fits post-R10 demand (no spill: FETCH ~1.3 KB).
// LDS must stay <= ~49K raw: 4-KiB granules, 3 blocks/CU needs <= 53248 alloc
// (R9 48128 -> 30% occ; R10 54272 -> 21%). This version: ~46.1 KB.
__global__ __launch_bounds__(256,3) void traj_kernel(Params p){
  __shared__ __align__(16) unsigned short w0b[DD][72];     // W0[a][i] bf16 (tangent A0)
  __shared__ __align__(16) float w3tt[HH][20];             // W3[j][a] fp32 (trace)
  __shared__ __align__(16) unsigned short w0t[HH][16];     // W0^T[jw][k<16] bf16 (L0 B-frag)
  __shared__ __align__(16) unsigned short b3f[2][64][8];   // L3 B-frags (lane-only)
  __shared__ __align__(16) unsigned short w2tf[2][4][64][8]; // tangent W2 B-frags (lane-only)
  __shared__ __align__(16) float4 lscA[3][64];             // {g,gb,hb,b} per col, layers 0-2
  __shared__ __align__(16) float4 lsc3[16];                // layer 3 (by m)
  __shared__ __align__(16) unsigned short xh[DD][16];      // x hi-bf16 (K>=16 via zero frag)
  __shared__ __align__(16) unsigned short xl[DD][16];      // x lo-bf16
  __shared__ __align__(16) unsigned short hbh[2][EPB][72]; // bf16 activations (ping-pong)
  __shared__ __align__(16) unsigned short sb[3][EPB][72];  // s0,s1,s2 bf16
  __shared__ __align__(16) float sig3w[4][DD];
  __shared__ __align__(16) float dxs[4][4][17];            // per-wave dx slice [wv][r][m]
  __shared__ __align__(16) unsigned short vt[4][DD][72];   // per-wave V1

  const int tid = threadIdx.x;
  const int e   = tid>>4;
  const int a   = tid&15;
  const int wv  = tid>>6;
  const int lane= tid&63;
  const int m   = lane&15;
  const int q   = lane>>4;
  const int b   = blockIdx.x*EPB + e;
  const int jw  = wv*16 + m;     // forward output column of this lane

  // ---- persistent register weight fragments (wave-dep or hottest reuse) ----
  short8 f1fr[2], f2fr[2];
  short8 b1fr[2][4];              // tangent GEMM1 B-frags, N-permuted: cols 4m+nt
  {
    #pragma unroll
    for(int kk=0;kk<2;++kk){
      #pragma unroll
      for(int j=0;j<8;++j){
        const int k=kk*32+q*8+j;
        f1fr[kk][j]=(short)f2bf(p.W1[k*HH+jw]);
        f2fr[kk][j]=(short)f2bf(p.W2[k*HH+jw]);
      }
      #pragma unroll
      for(int nt=0;nt<4;++nt){
        #pragma unroll
        for(int j=0;j<8;++j){
          const int k=kk*32+q*8+j;
          b1fr[kk][nt][j]=(short)f2bf(p.W1[k*HH+4*m+nt]);
        }
      }
    }
  }

  // ---- one-time LDS staging ----
  for(int idx=tid; idx<DD*HH; idx+=256) w0b[idx>>6][idx&63]=f2bf(p.W0[idx]);
  for(int idx=tid; idx<HH*DD; idx+=256) w3tt[idx>>4][idx&15]=p.W3[idx];   // fp32
  for(int idx=tid; idx<HH*16; idx+=256){
    const int c_=idx>>4, k=idx&15;
    w0t[c_][k]=f2bf(p.W0[k*HH+c_]);
  }
  for(int idx=tid; idx<1024; idx+=256){
    const int kk=idx>>9, ln=(idx>>3)&63, j=idx&7;
    const int k=kk*32+(ln>>4)*8+j;
    b3f[kk][ln][j]=f2bf(p.W3[k*DD+(ln&15)]);
  }
  for(int idx=tid; idx<4096; idx+=256){       // tangent W2 B-frags
    const int j=idx&7, ln=(idx>>3)&63, nt=(idx>>9)&3, kk=idx>>11;
    const int k=kk*32+((ln>>4)&3)*8+j;
    w2tf[kk][nt][ln][j]=f2bf(p.W2[k*HH+4*(ln&15)+nt]);
  }
  if(tid<64)            lscA[0][tid]    =make_float4(p.g0[tid],p.gb0[tid],p.hb0[tid],p.b0[tid]);
  else if(tid<128)      lscA[1][tid-64] =make_float4(p.g1[tid-64],p.gb1[tid-64],p.hb1[tid-64],p.b1[tid-64]);
  else if(tid<192)      lscA[2][tid-128]=make_float4(p.g2[tid-128],p.gb2[tid-128],p.hb2[tid-128],p.b2[tid-128]);
  else if(tid<208)      lsc3[tid-192]   =make_float4(p.g3[tid-192],p.gb3[tid-192],p.hb3[tid-192],p.b3[tid-192]);
  __syncthreads();

  float zbx = p.x0[b*DD+a];
  p.out[b*DD+a]=zbx;
  float trp[4]={0.f,0.f,0.f,0.f};
  float dvp=0.f;

  #pragma unroll 1
  for(int step=0; step<2; ++step){
    const float t0=p.ts[step], t1=p.ts[step+1];
    const float hs=t1-t0;
    float dzx=0.f;
    float zwx=zbx;
    #pragma unroll 1
    for(int stage=0; stage<4; ++stage){
      const float cin=(stage==0)?0.f:((stage==3)?1.f:0.5f);
      const float tcur=t0+cin*hs;
      const float wg=(stage==0||stage==3)?1.f:2.f;
      const float fs=hs*(1.f/6.f)*wg;
      const float fs5=0.5f*fs;

      // producer writes x as pre-split hi/lo bf16
      {
        const unsigned ux=__float_as_uint(zwx);
        xh[e][a]=(unsigned short)(ux>>16);
        xl[e][a]=f2bf1(zwx-__uint_as_float(ux&0xFFFF0000u));
      }
      __syncthreads();                       // B1

      // ---------- L0: X @ W0 (hi/lo; K>=16 rows zero via zero frags) ----------
      float4 sc0=lscA[0][jw];
      f32x4 c={sc0.w,sc0.w,sc0.w,sc0.w};
      {
        short8 f0fr=short8{0,0,0,0,0,0,0,0};
        short8 ah=f0fr, al=f0fr;
        if(q<2){
          f0fr=*reinterpret_cast<const short8*>(&w0t[jw][q*8]);
          ah  =*reinterpret_cast<const short8*>(&xh[m][q*8]);
          al  =*reinterpret_cast<const short8*>(&xl[m][q*8]);
        }
        c=MFMA(ah,f0fr,c); c=MFMA(al,f0fr,c);
      }
      fwd_epi(c,tcur,sc0,&hbh[0][0][0],&sb[0][0][0],jw,q);
      __syncthreads();                       // B2

      // ---------- L1 ----------
      float4 sc1=lscA[1][jw];
      c=f32x4{sc1.w,sc1.w,sc1.w,sc1.w};
      #pragma unroll
      for(int kk=0;kk<2;++kk){
        const short8 ah=*reinterpret_cast<const short8*>(&hbh[0][m][kk*32+q*8]);
        c=MFMA(ah,f1fr[kk],c);
      }
      fwd_epi(c,tcur,sc1,&hbh[1][0][0],&sb[1][0][0],jw,q);
      __syncthreads();                       // B3

      // ---------- L2 ----------
      float4 sc2=lscA[2][jw];
      c=f32x4{sc2.w,sc2.w,sc2.w,sc2.w};
      #pragma unroll
      for(int kk=0;kk<2;++kk){
        const short8 ah=*reinterpret_cast<const short8*>(&hbh[1][m][kk*32+q*8]);
        c=MFMA(ah,f2fr[kk],c);
      }
      fwd_epi(c,tcur,sc2,&hbh[0][0][0],&sb[2][0][0],jw,q);  // h2 -> buf0
      __syncthreads();                       // B4

      // ---------- L3: dx ----------
      float4 sc3=lsc3[m];
      c=f32x4{sc3.w,sc3.w,sc3.w,sc3.w};
      #pragma unroll
      for(int kk=0;kk<2;++kk){
        const short8 bf3=*reinterpret_cast<const short8*>(&b3f[kk][lane][0]);
        const short8 ah=*reinterpret_cast<const short8*>(&hbh[0][m][kk*32+q*8]);
        c=MFMA(ah,bf3,c);
      }
      const float gate3=sigm(tcur*sc3.x+sc3.y);
      const float tb3=tcur*sc3.z;
      if(q==wv){
        #pragma unroll
        for(int r=0;r<4;++r)
          dxs[wv][r][m]=c[r]*gate3+tb3;
      }
      if(q==0) sig3w[wv][m]=gate3;
      WV();
      const float dxk=dxs[wv][q][m];         // = dx[e][a]
      dvp += fs5*dxk*dxk;

      // ---------- trace factors (once per stage, pk) ----------
      f32x2 tf2[4][2];
      {
        const f32x4 sg4=*reinterpret_cast<const f32x4*>(&sig3w[wv][q*4]);
        const f32x2 sgA={sg4[0],sg4[1]}, sgB={sg4[2],sg4[3]};
        #pragma unroll
        for(int nt=0;nt<4;++nt){
          const f32x4 w4=*reinterpret_cast<const f32x4*>(&w3tt[4*m+nt][q*4]);
          tf2[nt][0]=sgA*f32x2{w4[0],w4[1]};
          tf2[nt][1]=sgB*f32x2{w4[2],w4[3]};
        }
      }

      // ---------- tangent per element (nt-paired accumulators) ----------
      #pragma unroll
      for(int el=0; el<4; ++el){
        const int ee=wv*4+el;
        // A0 = W0 (bf16) ⊙ s0 (bf16): dword-packed unpack+mul+repack
        Frag a0[2];
        #pragma unroll
        for(int kk=0;kk<2;++kk){
          const uint4v wd=*reinterpret_cast<const uint4v*>(&w0b[m][kk*32+q*8]);
          const uint4v sd=*reinterpret_cast<const uint4v*>(&sb[0][ee][kk*32+q*8]);
          #pragma unroll
          for(int d=0;d<4;++d){
            const unsigned w2d=wd[d], s2d=sd[d];
            const float wlo=__uint_as_float(w2d<<16), whi=__uint_as_float(w2d&0xFFFF0000u);
            const float slo=__uint_as_float(s2d<<16), shi=__uint_as_float(s2d&0xFFFF0000u);
            a0[kk].d[d]=pk2bf(wlo*slo,whi*shi);
          }
        }
        // GEMM1 in nt pairs: only 2 acc quads live
        #pragma unroll
        for(int np=0; np<2; ++np){
          f32x4 cA={0,0,0,0}, cB={0,0,0,0};
          #pragma unroll
          for(int kk=0;kk<2;++kk){
            cA=MFMA(a0[kk].s,b1fr[kk][2*np  ],cA);
            cB=MFMA(a0[kk].s,b1fr[kk][2*np+1],cB);
          }
          const unsigned s1d=*reinterpret_cast<const unsigned*>(&sb[1][ee][4*m+2*np]);
          const float sA_=__uint_as_float(s1d<<16), sB_=__uint_as_float(s1d&0xFFFF0000u);
          const f32x4 prA=cA*sA_, prB=cB*sB_;
          #pragma unroll
          for(int r=0;r<4;++r)
            *reinterpret_cast<unsigned*>(&vt[wv][q*4+r][4*m+2*np])=pk2bf(prA[r],prB[r]);
        }
        WV();
        short8 a2[2];
        #pragma unroll
        for(int kk=0;kk<2;++kk)
          a2[kk]=*reinterpret_cast<const short8*>(&vt[wv][m][kk*32+q*8]);
        // GEMM2 in nt pairs, B-frags streamed from LDS (lane-only table)
        float tr=0.f;
        #pragma unroll
        for(int np=0; np<2; ++np){
          f32x4 cA={0,0,0,0}, cB={0,0,0,0};
          #pragma unroll
          for(int kk=0;kk<2;++kk){
            const short8 bA=*reinterpret_cast<const short8*>(&w2tf[kk][2*np  ][lane][0]);
            const short8 bB=*reinterpret_cast<const short8*>(&w2tf[kk][2*np+1][lane][0]);
            cA=MFMA(a2[kk],bA,cA);
            cB=MFMA(a2[kk],bB,cB);
          }
          const unsigned s2d=*reinterpret_cast<const unsigned*>(&sb[2][ee][4*m+2*np]);
          const float s20=__uint_as_float(s2d<<16), s21=__uint_as_float(s2d&0xFFFF0000u);
          const f32x2 tA = f32x2{cA[0],cA[1]}*tf2[2*np  ][0] + f32x2{cA[2],cA[3]}*tf2[2*np  ][1];
          const f32x2 tB = f32x2{cB[0],cB[1]}*tf2[2*np+1][0] + f32x2{cB[2],cB[3]}*tf2[2*np+1][1];
          tr += (tA[0]+tA[1])*s20 + (tB[0]+tB[1])*s21;
        }
        trp[el] += fs*tr;
        WV();
      }

      // ---------- RK4 state update ----------
      dzx += fs*dxk;
      const float cn=(stage==2)?1.f:0.5f;
      if(stage<3) zwx=zbx+cn*hs*dxk;
    }
    zbx += dzx;
    p.out[(step+1)*(NB*DD)+b*DD+a]=zbx;
  }

  // ---------- deferred reductions ----------
  #pragma unroll
  for(int el=0; el<4; ++el){
    float v=trp[el];
    #pragma unroll
    for(int mk=32;mk>=1;mk>>=1) v+=__shfl_xor(v,mk,64);
    if(lane==el) p.out[3*NB*DD + blockIdx.x*EPB + wv*4 + el]=v;
  }
  {
    float v=dvp;
    #pragma unroll
    for(int mk=8;mk>=1;mk>>=1) v+=__shfl_xor(v,mk,16);
    if(a==0){
      p.out[3*NB*DD+NB+b]=fabsf(v);
      p.out[3*NB*DD+2*NB+b]=0.f;
    }
  }
}

extern "C" void kernel_launch(void* const* d_in, const int* in_sizes, int n_in,
                              void* d_out, int out_size, void* d_ws, size_t ws_size,
                              hipStream_t stream){
  Params p;
  p.ts  = (const float*)d_in[0];
  p.x0  = (const float*)d_in[1];
  p.W0  = (const float*)d_in[2];  p.b0 =(const float*)d_in[3];
  p.g0  = (const float*)d_in[4];  p.gb0=(const float*)d_in[5];  p.hb0=(const float*)d_in[6];
  p.W1  = (const float*)d_in[7];  p.b1 =(const float*)d_in[8];
  p.g1  = (const float*)d_in[9];  p.gb1=(const float*)d_in[10]; p.hb1=(const float*)d_in[11];
  p.W2  = (const float*)d_in[12]; p.b2 =(const float*)d_in[13];
  p.g2  = (const float*)d_in[14]; p.gb2=(const float*)d_in[15]; p.hb2=(const float*)d_in[16];
  p.W3  = (const float*)d_in[17]; p.b3 =(const float*)d_in[18];
  p.g3  = (const float*)d_in[19]; p.gb3=(const float*)d_in[20]; p.hb3=(const float*)d_in[21];
  p.out = (float*)d_out;
  hipLaunchKernelGGL(traj_kernel, dim3(NB/EPB), dim3(256), 0, stream, p);
}